// Round 1
// baseline (1938.103 us; speedup 1.0000x reference)
//
#include <hip/hip_runtime.h>

#define B_   16
#define N_   4096
#define CIN  64
#define COUT 128
#define NPT  1024
#define KNNK 16

__device__ __forceinline__ float fINF() { return __int_as_float(0x7f800000); }

// ---------------------------------------------------------------------------
// K1: farthest point sampling. One block per batch, 256 threads.
// p staged in LDS (SoA) + per-thread register tiles (16 points each).
// Replicates jnp.argmax tie-break (lowest index wins on equal values).
// ---------------------------------------------------------------------------
__global__ __launch_bounds__(256) void fps_kernel(const float* __restrict__ p,
                                                  int* __restrict__ idx_out,
                                                  float* __restrict__ newp_out) {
    __shared__ float sx[N_], sy[N_], sz[N_];
    __shared__ int   sidx[NPT];
    __shared__ float rv[4];
    __shared__ int   ri[4];

    const int b = blockIdx.x;
    const int t = threadIdx.x;
    const float* pb = p + (size_t)b * N_ * 3;

    // coalesced stage of p into LDS (12288 floats)
    for (int i = 0; i < 48; ++i) {
        int f = t + 256 * i;
        float v = pb[f];
        int pt = f / 3, c = f - pt * 3;
        if (c == 0) sx[pt] = v; else if (c == 1) sy[pt] = v; else sz[pt] = v;
    }
    __syncthreads();

    float lx[16], ly[16], lz[16], dist[16];
#pragma unroll
    for (int j = 0; j < 16; ++j) {
        int i = t + 256 * j;
        lx[j] = sx[i]; ly[j] = sy[i]; lz[j] = sz[i];
        dist[j] = 1e10f;
    }

    int far = 0;
    if (t == 0) sidx[0] = 0;
    const int wave = t >> 6, lane = t & 63;

    for (int s = 1; s < NPT; ++s) {
        const float cx = sx[far], cy = sy[far], cz = sz[far];
        float bv = -1.0f; int bi = 0;
#pragma unroll
        for (int j = 0; j < 16; ++j) {
            float dx = lx[j] - cx, dy = ly[j] - cy, dz = lz[j] - cz;
            float d = dx * dx + dy * dy + dz * dz;
            float nd = fminf(dist[j], d);
            dist[j] = nd;
            if (nd > bv) { bv = nd; bi = t + 256 * j; }   // strict >: keeps lowest idx
        }
        // wave64 butterfly argmax, tie -> lower index
#pragma unroll
        for (int off = 32; off >= 1; off >>= 1) {
            float ov = __shfl_xor(bv, off);
            int   oi = __shfl_xor(bi, off);
            if (ov > bv || (ov == bv && oi < bi)) { bv = ov; bi = oi; }
        }
        if (lane == 0) { rv[wave] = bv; ri[wave] = bi; }
        __syncthreads();
        if (t == 0) {
            float v0 = rv[0]; int i0 = ri[0];
#pragma unroll
            for (int w = 1; w < 4; ++w) {
                float v = rv[w]; int i = ri[w];
                if (v > v0 || (v == v0 && i < i0)) { v0 = v; i0 = i; }
            }
            sidx[s] = i0;
        }
        __syncthreads();
        far = sidx[s];
    }

    // outputs: sampled indices + new_p (second section of d_out)
    for (int s = t; s < NPT; s += 256) {
        int i = sidx[s];
        idx_out[b * NPT + s] = i;
        float* np = newp_out + ((size_t)b * NPT + s) * 3;
        np[0] = sx[i]; np[1] = sy[i]; np[2] = sz[i];
    }
}

// ---------------------------------------------------------------------------
// K2: KNN. One block (256 thr) per query; 17 min-extraction rounds
// (round 0 = the self point, dropped -> replicates top_k(...)[...,1:]).
// Tie-break: lower candidate index (lax.top_k stability).
// ---------------------------------------------------------------------------
__global__ __launch_bounds__(256) void knn_kernel(const float* __restrict__ p,
                                                  const int* __restrict__ idx_in,
                                                  int* __restrict__ knn_out) {
    __shared__ float rv[4];
    __shared__ int   ri[4];
    __shared__ int   wsh;

    const int blk = blockIdx.x;
    const int b = blk >> 10, n = blk & 1023;
    const int t = threadIdx.x;
    const float* pb = p + (size_t)b * N_ * 3;

    const int qi = idx_in[b * NPT + n];
    const float qx = pb[qi * 3 + 0], qy = pb[qi * 3 + 1], qz = pb[qi * 3 + 2];

    float dist[16];
#pragma unroll
    for (int j = 0; j < 16; ++j) {
        int i = t + 256 * j;
        float dx = pb[i * 3 + 0] - qx;
        float dy = pb[i * 3 + 1] - qy;
        float dz = pb[i * 3 + 2] - qz;
        dist[j] = dx * dx + dy * dy + dz * dz;
    }

    const int wave = t >> 6, lane = t & 63;
    int* kout = knn_out + ((size_t)b * NPT + n) * KNNK;

    for (int r = 0; r < 17; ++r) {
        float bv = fINF(); int bi = 0x7fffffff;
#pragma unroll
        for (int j = 0; j < 16; ++j) {
            float d = dist[j];
            int i = t + 256 * j;
            if (d < bv) { bv = d; bi = i; }   // strict <: keeps lowest idx
        }
#pragma unroll
        for (int off = 32; off >= 1; off >>= 1) {
            float ov = __shfl_xor(bv, off);
            int   oi = __shfl_xor(bi, off);
            if (ov < bv || (ov == bv && oi < bi)) { bv = ov; bi = oi; }
        }
        if (lane == 0) { rv[wave] = bv; ri[wave] = bi; }
        __syncthreads();
        if (t == 0) {
            float v0 = rv[0]; int i0 = ri[0];
#pragma unroll
            for (int w = 1; w < 4; ++w) {
                float v = rv[w]; int i = ri[w];
                if (v < v0 || (v == v0 && i < i0)) { v0 = v; i0 = i; }
            }
            wsh = i0;
            if (r > 0) kout[r - 1] = i0;
        }
        __syncthreads();
        const int wi = wsh;
        const bool mine = (wi & 255) == t;
        const int slot = wi >> 8;
#pragma unroll
        for (int j = 0; j < 16; ++j)
            if (mine && slot == j) dist[j] = fINF();
    }
}

// ---------------------------------------------------------------------------
// K3: second-moment stats of diff. mean/var of h are derived analytically:
//   mean_o = w_o . E[d],  E[h_o^2] = w_o^T E[dd^T] w_o.
// 256 blocks, each accumulates 1024 samples into a 64x64 partial (4x4 tile
// per thread, in registers), written as deterministic block partials.
// ---------------------------------------------------------------------------
__global__ __launch_bounds__(256) void stats_kernel(const float* __restrict__ x,
                                                    const int* __restrict__ idx_in,
                                                    const int* __restrict__ knn_in,
                                                    float* __restrict__ part) {
    __shared__ float xc[4 * 64];
    __shared__ float dls[64 * 72];   // 64 samples x 64 ch, row stride 72 (b128-aligned)

    const int blk = blockIdx.x;      // 0..255
    const int t = threadIdx.x;
    const int q0 = blk * 64;         // 64 queries per block (stays within one batch)
    const int b = q0 >> 10;
    const float* xb = x + (size_t)b * N_ * CIN;

    float acc[4][4];
#pragma unroll
    for (int i = 0; i < 4; ++i)
#pragma unroll
        for (int j = 0; j < 4; ++j) acc[i][j] = 0.f;
    float dsum = 0.f;

    const int r0 = (t >> 4) * 4, c0 = (t & 15) * 4;

    for (int sg = 0; sg < 16; ++sg) {
        __syncthreads();
        {   // stage 4 query centers
            int qq = t >> 6, c = t & 63;
            int q = q0 + sg * 4 + qq;
            int ci = idx_in[q];
            xc[qq * 64 + c] = xb[ci * CIN + c];
        }
        __syncthreads();
        // stage 64 diff vectors
        for (int i = 0; i < 16; ++i) {
            int f = t + 256 * i;                 // 0..4095
            int qq = f >> 10, k = (f >> 6) & 15, c = f & 63;
            int q = q0 + sg * 4 + qq;
            int row = knn_in[q * KNNK + k];
            dls[(qq * 16 + k) * 72 + c] = xc[qq * 64 + c] - xb[row * CIN + c];
        }
        __syncthreads();
        // accumulate outer products
#pragma unroll 4
        for (int s = 0; s < 64; ++s) {
            const float4 a  = *(const float4*)&dls[s * 72 + r0];
            const float4 bb = *(const float4*)&dls[s * 72 + c0];
            acc[0][0] += a.x * bb.x; acc[0][1] += a.x * bb.y; acc[0][2] += a.x * bb.z; acc[0][3] += a.x * bb.w;
            acc[1][0] += a.y * bb.x; acc[1][1] += a.y * bb.y; acc[1][2] += a.y * bb.z; acc[1][3] += a.y * bb.w;
            acc[2][0] += a.z * bb.x; acc[2][1] += a.z * bb.y; acc[2][2] += a.z * bb.z; acc[2][3] += a.z * bb.w;
            acc[3][0] += a.w * bb.x; acc[3][1] += a.w * bb.y; acc[3][2] += a.w * bb.z; acc[3][3] += a.w * bb.w;
        }
        if (t < 64) {
            for (int s = 0; s < 64; ++s) dsum += dls[s * 72 + t];
        }
    }

    float* pout = part + (size_t)blk * 4160;
#pragma unroll
    for (int i = 0; i < 4; ++i)
#pragma unroll
        for (int j = 0; j < 4; ++j)
            pout[(r0 + i) * 64 + (c0 + j)] = acc[i][j];
    if (t < 64) pout[4096 + t] = dsum;
}

// K4a: reduce 256 block partials -> M[4096] + dsum[64]
__global__ __launch_bounds__(256) void reduce_kernel(const float* __restrict__ part,
                                                     float* __restrict__ M) {
    int e = blockIdx.x * 256 + threadIdx.x;
    if (e >= 4160) return;
    float s = 0.f;
    for (int b = 0; b < 256; ++b) s += part[(size_t)b * 4160 + e];
    M[e] = s;
}

// K4b: per output channel o: mean/var -> fused scale/shift
__global__ __launch_bounds__(64) void scale_kernel(const float* __restrict__ M,
                                                   const float* __restrict__ w,
                                                   const float* __restrict__ gamma,
                                                   const float* __restrict__ beta,
                                                   float* __restrict__ st) {
    __shared__ float wv[64];
    const int o = blockIdx.x, t = threadIdx.x;
    wv[t] = w[o * 64 + t];
    __syncthreads();
    const float* Mr = M + t * 64;
    float sr = 0.f;
    for (int c = 0; c < 64; ++c) sr += Mr[c] * wv[c];
    float e2 = wv[t] * sr;
    float mn = wv[t] * M[4096 + t];
#pragma unroll
    for (int off = 32; off >= 1; off >>= 1) {
        e2 += __shfl_xor(e2, off);
        mn += __shfl_xor(mn, off);
    }
    if (t == 0) {
        const float Ns = 262144.0f;
        float mean = mn / Ns;
        float var = e2 / Ns - mean * mean;
        float scale = gamma[o] * rsqrtf(var + 1e-5f);
        st[o] = scale;
        st[128 + o] = beta[o] - mean * scale;
    }
}

// ---------------------------------------------------------------------------
// K5: fused diff -> conv(1x1) -> affine-norm -> relu -> max over k.
// One block per query. wT staged transposed in LDS (conflict-free writes),
// diff in LDS (2-way aliasing = free). Thread = (k, 8-wide o-group).
// ---------------------------------------------------------------------------
__global__ __launch_bounds__(256) void out_kernel(const float* __restrict__ x,
                                                  const float* __restrict__ w,
                                                  const int* __restrict__ idx_in,
                                                  const int* __restrict__ knn_in,
                                                  const float* __restrict__ st,
                                                  float* __restrict__ out) {
    __shared__ float wT[64 * 132];
    __shared__ float df[16 * 68];
    __shared__ float xc[64];
    __shared__ float ss[256];
    __shared__ float hred[16 * 132];

    const int blk = blockIdx.x;
    const int b = blk >> 10, n = blk & 1023;
    const int t = threadIdx.x;
    const float* xb = x + (size_t)b * N_ * CIN;

    if (t < 64) {
        int ci = idx_in[b * NPT + n];
        xc[t] = xb[ci * CIN + t];
    }
    ss[t] = st[t];
    {   // wT[c][o] = w[o][c]; per-wave consecutive o, uniform c -> conflict-free LDS writes
        int o = t & 127, cbase = t >> 7;
        for (int i = 0; i < 32; ++i) {
            int c = cbase + 2 * i;
            wT[c * 132 + o] = w[o * 64 + c];
        }
    }
    __syncthreads();

    const int* kr = knn_in + ((size_t)b * NPT + n) * KNNK;
    for (int i = 0; i < 4; ++i) {
        int f = t + 256 * i;
        int k = f >> 6, c = f & 63;
        int row = kr[k];
        df[k * 68 + c] = xc[c] - xb[row * CIN + c];
    }
    __syncthreads();

    const int k = t & 15, oq = t >> 4;   // 16 k x 16 o-groups of 8
    float h[8];
#pragma unroll
    for (int i = 0; i < 8; ++i) h[i] = 0.f;
    const float* drow = &df[k * 68];
    for (int c = 0; c < 64; ++c) {
        float d = drow[c];
        const float4 w0 = *(const float4*)&wT[c * 132 + oq * 8 + 0];
        const float4 w1 = *(const float4*)&wT[c * 132 + oq * 8 + 4];
        h[0] += d * w0.x; h[1] += d * w0.y; h[2] += d * w0.z; h[3] += d * w0.w;
        h[4] += d * w1.x; h[5] += d * w1.y; h[6] += d * w1.z; h[7] += d * w1.w;
    }

#pragma unroll
    for (int i = 0; i < 8; ++i) {
        int o = oq * 8 + i;
        float v = fmaxf(h[i] * ss[o] + ss[128 + o], 0.f);
        hred[k * 132 + o] = v;
    }
    __syncthreads();

    if (t < 128) {
        float m = hred[t];
#pragma unroll
        for (int kk = 1; kk < 16; ++kk) m = fmaxf(m, hred[kk * 132 + t]);
        out[((size_t)b * NPT + n) * COUT + t] = m;
    }
}

// ---------------------------------------------------------------------------
extern "C" void kernel_launch(void* const* d_in, const int* in_sizes, int n_in,
                              void* d_out, int out_size, void* d_ws, size_t ws_size,
                              hipStream_t stream) {
    const float* x     = (const float*)d_in[0];
    const float* p     = (const float*)d_in[1];
    const float* w     = (const float*)d_in[2];
    const float* gamma = (const float*)d_in[3];
    const float* beta  = (const float*)d_in[4];

    float* out  = (float*)d_out;                               // [16,1024,128]
    float* newp = out + (size_t)B_ * NPT * COUT;               // [16,1024,3]

    char* ws = (char*)d_ws;
    int*   idx  = (int*)(ws + 0);           // 16384 ints
    int*   knn  = (int*)(ws + 65536);       // 262144 ints
    float* part = (float*)(ws + 1114112);   // 256*4160 floats
    float* M    = (float*)(ws + 5373952);   // 4160 floats
    float* st   = (float*)(ws + 5390592);   // 256 floats

    hipLaunchKernelGGL(fps_kernel,   dim3(B_),        dim3(256), 0, stream, p, idx, newp);
    hipLaunchKernelGGL(knn_kernel,   dim3(B_ * NPT),  dim3(256), 0, stream, p, idx, knn);
    hipLaunchKernelGGL(stats_kernel, dim3(256),       dim3(256), 0, stream, x, idx, knn, part);
    hipLaunchKernelGGL(reduce_kernel,dim3(17),        dim3(256), 0, stream, part, M);
    hipLaunchKernelGGL(scale_kernel, dim3(128),       dim3(64),  0, stream, M, w, gamma, beta, st);
    hipLaunchKernelGGL(out_kernel,   dim3(B_ * NPT),  dim3(256), 0, stream, x, w, idx, knn, st, out);
}

// Round 2
// 1261.006 us; speedup vs baseline: 1.5369x; 1.5369x over previous
//
#include <hip/hip_runtime.h>

#define B_   16
#define N_   4096
#define CIN  64
#define COUT 128
#define NPT  1024
#define KNNK 16

__device__ __forceinline__ float fINF() { return __int_as_float(0x7f800000); }

// ---------------------------------------------------------------------------
// K1: farthest point sampling. One block of 1024 threads per batch (16 waves
// -> 4 waves/SIMD for latency hiding). Per step: register min-update +
// value-only fmaxf butterfly + cross-wave LDS atomicMax(float-as-int,
// valid for non-negative) + argmax tie-break via LDS atomicMin on global
// index of exact-match threads (= jnp.argmax first-max semantics).
// Double-buffered winner/max slots -> 2 barriers/step.
// ---------------------------------------------------------------------------
__global__ __launch_bounds__(1024) void fps_kernel(const float* __restrict__ p,
                                                   int* __restrict__ idx_out,
                                                   float* __restrict__ newp_out) {
    __shared__ float sx[N_], sy[N_], sz[N_];
    __shared__ int   sidx[NPT];
    __shared__ int   swin[2];
    __shared__ int   sMv[2];

    const int b = blockIdx.x;
    const int t = threadIdx.x;
    const float* pb = p + (size_t)b * N_ * 3;

    // coalesced stage of p into LDS (12288 floats)
    for (int i = 0; i < 12; ++i) {
        int f = t + 1024 * i;
        float v = pb[f];
        int pt = f / 3, c = f - pt * 3;
        if (c == 0) sx[pt] = v; else if (c == 1) sy[pt] = v; else sz[pt] = v;
    }
    if (t < 2) { swin[t] = 0x7fffffff; sMv[t] = 0; }
    __syncthreads();

    float lx[4], ly[4], lz[4], dist[4];
#pragma unroll
    for (int j = 0; j < 4; ++j) {
        int i = t + 1024 * j;
        lx[j] = sx[i]; ly[j] = sy[i]; lz[j] = sz[i];
        dist[j] = 1e10f;
    }

    int far = 0;
    if (t == 0) sidx[0] = 0;
    const int lane = t & 63;

    for (int s = 1; s < NPT; ++s) {
        const int par = s & 1;
        // ---- region A: update + value-only wave max ----
        const float cx = sx[far], cy = sy[far], cz = sz[far];
        float nd0, nd1, nd2, nd3;
        {
            float dx, dy, dz, d;
            dx = lx[0]-cx; dy = ly[0]-cy; dz = lz[0]-cz; d = dx*dx + dy*dy + dz*dz;
            nd0 = fminf(dist[0], d); dist[0] = nd0;
            dx = lx[1]-cx; dy = ly[1]-cy; dz = lz[1]-cz; d = dx*dx + dy*dy + dz*dz;
            nd1 = fminf(dist[1], d); dist[1] = nd1;
            dx = lx[2]-cx; dy = ly[2]-cy; dz = lz[2]-cz; d = dx*dx + dy*dy + dz*dz;
            nd2 = fminf(dist[2], d); dist[2] = nd2;
            dx = lx[3]-cx; dy = ly[3]-cy; dz = lz[3]-cz; d = dx*dx + dy*dy + dz*dz;
            nd3 = fminf(dist[3], d); dist[3] = nd3;
        }
        float bv = fmaxf(fmaxf(nd0, nd1), fmaxf(nd2, nd3));
#pragma unroll
        for (int off = 32; off >= 1; off >>= 1)
            bv = fmaxf(bv, __shfl_xor(bv, off));
        if (lane == 0) atomicMax(&sMv[par], __float_as_int(bv));
        __syncthreads();
        // ---- region B: match + index tie-break ----
        if (t == 0) { sMv[par ^ 1] = 0; swin[par ^ 1] = 0x7fffffff; }
        const float M = __int_as_float(sMv[par]);
        if (dist[0] == M) atomicMin(&swin[par], t);
        if (dist[1] == M) atomicMin(&swin[par], t + 1024);
        if (dist[2] == M) atomicMin(&swin[par], t + 2048);
        if (dist[3] == M) atomicMin(&swin[par], t + 3072);
        __syncthreads();
        // ---- region C ----
        far = swin[par];
        if (t == 0) sidx[s] = far;
    }

    // outputs: sampled indices + new_p (second section of d_out)
    {
        int i = sidx[t];
        idx_out[b * NPT + t] = i;
        float* np = newp_out + ((size_t)b * NPT + t) * 3;
        np[0] = sx[i]; np[1] = sy[i]; np[2] = sz[i];
    }
}

// ---------------------------------------------------------------------------
// K2: KNN. One block (256 thr) per query; 17 min-extraction rounds
// (round 0 = self point, dropped -> replicates top_k(...)[...,1:]).
// Cached per-thread local min: only the owner of the removed point rescans.
// Value reduce: fminf butterfly + LDS atomicMin(float-as-int); index
// tie-break (lower index = lax.top_k stability) via LDS atomicMin.
// ---------------------------------------------------------------------------
__global__ __launch_bounds__(256) void knn_kernel(const float* __restrict__ p,
                                                  const int* __restrict__ idx_in,
                                                  int* __restrict__ knn_out) {
    __shared__ int swin[2];
    __shared__ int sMv[2];

    const int blk = blockIdx.x;
    const int b = blk >> 10, n = blk & 1023;
    const int t = threadIdx.x;
    const float* pb = p + (size_t)b * N_ * 3;

    const int qi = idx_in[b * NPT + n];
    const float qx = pb[qi * 3 + 0], qy = pb[qi * 3 + 1], qz = pb[qi * 3 + 2];

    float dist[16];
#pragma unroll
    for (int j = 0; j < 16; ++j) {
        int i = t + 256 * j;
        float dx = pb[i * 3 + 0] - qx;
        float dy = pb[i * 3 + 1] - qy;
        float dz = pb[i * 3 + 2] - qz;
        dist[j] = dx * dx + dy * dy + dz * dz;
    }
    if (t < 2) { swin[t] = 0x7fffffff; sMv[t] = 0x7fffffff; }

    // cached local min (value only), pairwise tree
    float lmin;
    {
        float m0 = fminf(fminf(dist[0], dist[1]), fminf(dist[2], dist[3]));
        float m1 = fminf(fminf(dist[4], dist[5]), fminf(dist[6], dist[7]));
        float m2 = fminf(fminf(dist[8], dist[9]), fminf(dist[10], dist[11]));
        float m3 = fminf(fminf(dist[12], dist[13]), fminf(dist[14], dist[15]));
        lmin = fminf(fminf(m0, m1), fminf(m2, m3));
    }
    __syncthreads();

    const int lane = t & 63;
    int* kout = knn_out + ((size_t)b * NPT + n) * KNNK;

    for (int r = 0; r < 17; ++r) {
        const int par = r & 1;
        // ---- region A: value-only wave min over cached lmins ----
        float wv = lmin;
#pragma unroll
        for (int off = 32; off >= 1; off >>= 1)
            wv = fminf(wv, __shfl_xor(wv, off));
        if (lane == 0) atomicMin(&sMv[par], __float_as_int(wv));
        __syncthreads();
        // ---- region B ----
        if (t == 0) { sMv[par ^ 1] = 0x7fffffff; swin[par ^ 1] = 0x7fffffff; }
        const float M = __int_as_float(sMv[par]);
        if (lmin == M) {
            int cand = 0x7fffffff;
#pragma unroll
            for (int j = 15; j >= 0; --j)
                if (dist[j] == M) cand = t + 256 * j;   // descending -> keeps lowest j
            atomicMin(&swin[par], cand);
        }
        __syncthreads();
        // ---- region C ----
        const int wi = swin[par];
        if (t == 0 && r > 0) kout[r - 1] = wi;
        if ((wi & 255) == t) {
            dist[wi >> 8] = fINF();
            float m0 = fminf(fminf(dist[0], dist[1]), fminf(dist[2], dist[3]));
            float m1 = fminf(fminf(dist[4], dist[5]), fminf(dist[6], dist[7]));
            float m2 = fminf(fminf(dist[8], dist[9]), fminf(dist[10], dist[11]));
            float m3 = fminf(fminf(dist[12], dist[13]), fminf(dist[14], dist[15]));
            lmin = fminf(fminf(m0, m1), fminf(m2, m3));
        }
    }
}

// ---------------------------------------------------------------------------
// K3: second-moment stats of diff. mean/var of h are derived analytically:
//   mean_o = w_o . E[d],  E[h_o^2] = w_o^T E[dd^T] w_o.
// 256 blocks, each accumulates 1024 samples into a 64x64 partial (4x4 tile
// per thread, in registers), written as deterministic block partials.
// ---------------------------------------------------------------------------
__global__ __launch_bounds__(256) void stats_kernel(const float* __restrict__ x,
                                                    const int* __restrict__ idx_in,
                                                    const int* __restrict__ knn_in,
                                                    float* __restrict__ part) {
    __shared__ float xc[4 * 64];
    __shared__ float dls[64 * 72];   // 64 samples x 64 ch, row stride 72 (b128-aligned)

    const int blk = blockIdx.x;      // 0..255
    const int t = threadIdx.x;
    const int q0 = blk * 64;         // 64 queries per block (stays within one batch)
    const int b = q0 >> 10;
    const float* xb = x + (size_t)b * N_ * CIN;

    float acc[4][4];
#pragma unroll
    for (int i = 0; i < 4; ++i)
#pragma unroll
        for (int j = 0; j < 4; ++j) acc[i][j] = 0.f;
    float dsum = 0.f;

    const int r0 = (t >> 4) * 4, c0 = (t & 15) * 4;

    for (int sg = 0; sg < 16; ++sg) {
        __syncthreads();
        {   // stage 4 query centers
            int qq = t >> 6, c = t & 63;
            int q = q0 + sg * 4 + qq;
            int ci = idx_in[q];
            xc[qq * 64 + c] = xb[ci * CIN + c];
        }
        __syncthreads();
        // stage 64 diff vectors
        for (int i = 0; i < 16; ++i) {
            int f = t + 256 * i;                 // 0..4095
            int qq = f >> 10, k = (f >> 6) & 15, c = f & 63;
            int q = q0 + sg * 4 + qq;
            int row = knn_in[q * KNNK + k];
            dls[(qq * 16 + k) * 72 + c] = xc[qq * 64 + c] - xb[row * CIN + c];
        }
        __syncthreads();
        // accumulate outer products
#pragma unroll 4
        for (int s = 0; s < 64; ++s) {
            const float4 a  = *(const float4*)&dls[s * 72 + r0];
            const float4 bb = *(const float4*)&dls[s * 72 + c0];
            acc[0][0] += a.x * bb.x; acc[0][1] += a.x * bb.y; acc[0][2] += a.x * bb.z; acc[0][3] += a.x * bb.w;
            acc[1][0] += a.y * bb.x; acc[1][1] += a.y * bb.y; acc[1][2] += a.y * bb.z; acc[1][3] += a.y * bb.w;
            acc[2][0] += a.z * bb.x; acc[2][1] += a.z * bb.y; acc[2][2] += a.z * bb.z; acc[2][3] += a.z * bb.w;
            acc[3][0] += a.w * bb.x; acc[3][1] += a.w * bb.y; acc[3][2] += a.w * bb.z; acc[3][3] += a.w * bb.w;
        }
        if (t < 64) {
            for (int s = 0; s < 64; ++s) dsum += dls[s * 72 + t];
        }
    }

    float* pout = part + (size_t)blk * 4160;
#pragma unroll
    for (int i = 0; i < 4; ++i)
#pragma unroll
        for (int j = 0; j < 4; ++j)
            pout[(r0 + i) * 64 + (c0 + j)] = acc[i][j];
    if (t < 64) pout[4096 + t] = dsum;
}

// K4a: reduce 256 block partials -> M[4096] + dsum[64]
__global__ __launch_bounds__(256) void reduce_kernel(const float* __restrict__ part,
                                                     float* __restrict__ M) {
    int e = blockIdx.x * 256 + threadIdx.x;
    if (e >= 4160) return;
    float s = 0.f;
    for (int b = 0; b < 256; ++b) s += part[(size_t)b * 4160 + e];
    M[e] = s;
}

// K4b: per output channel o: mean/var -> fused scale/shift
__global__ __launch_bounds__(64) void scale_kernel(const float* __restrict__ M,
                                                   const float* __restrict__ w,
                                                   const float* __restrict__ gamma,
                                                   const float* __restrict__ beta,
                                                   float* __restrict__ st) {
    __shared__ float wv[64];
    const int o = blockIdx.x, t = threadIdx.x;
    wv[t] = w[o * 64 + t];
    __syncthreads();
    const float* Mr = M + t * 64;
    float sr = 0.f;
    for (int c = 0; c < 64; ++c) sr += Mr[c] * wv[c];
    float e2 = wv[t] * sr;
    float mn = wv[t] * M[4096 + t];
#pragma unroll
    for (int off = 32; off >= 1; off >>= 1) {
        e2 += __shfl_xor(e2, off);
        mn += __shfl_xor(mn, off);
    }
    if (t == 0) {
        const float Ns = 262144.0f;
        float mean = mn / Ns;
        float var = e2 / Ns - mean * mean;
        float scale = gamma[o] * rsqrtf(var + 1e-5f);
        st[o] = scale;
        st[128 + o] = beta[o] - mean * scale;
    }
}

// ---------------------------------------------------------------------------
// K5: fused diff -> conv(1x1) -> affine-norm -> relu -> max over k.
// One block per query. w staged transposed in LDS via COALESCED global loads
// (fix vs R0: was stride-256B uncoalesced); diff in LDS. Thread = (k, 8-o).
// ---------------------------------------------------------------------------
__global__ __launch_bounds__(256) void out_kernel(const float* __restrict__ x,
                                                  const float* __restrict__ w,
                                                  const int* __restrict__ idx_in,
                                                  const int* __restrict__ knn_in,
                                                  const float* __restrict__ st,
                                                  float* __restrict__ out) {
    __shared__ float wT[64 * 132];
    __shared__ float df[16 * 68];
    __shared__ float xc[64];
    __shared__ float ss[256];
    __shared__ float hred[16 * 132];

    const int blk = blockIdx.x;
    const int b = blk >> 10, n = blk & 1023;
    const int t = threadIdx.x;
    const float* xb = x + (size_t)b * N_ * CIN;

    if (t < 64) {
        int ci = idx_in[b * NPT + n];
        xc[t] = xb[ci * CIN + t];
    }
    ss[t] = st[t];
    {   // coalesced: consecutive t -> consecutive c within one row o
        for (int i = 0; i < 32; ++i) {
            int f = t + 256 * i;
            int o = f >> 6, c = f & 63;
            wT[c * 132 + o] = w[f];
        }
    }
    __syncthreads();

    const int* kr = knn_in + ((size_t)b * NPT + n) * KNNK;
    for (int i = 0; i < 4; ++i) {
        int f = t + 256 * i;
        int k = f >> 6, c = f & 63;
        int row = kr[k];
        df[k * 68 + c] = xc[c] - xb[row * CIN + c];
    }
    __syncthreads();

    const int k = t & 15, oq = t >> 4;   // 16 k x 16 o-groups of 8
    float h[8];
#pragma unroll
    for (int i = 0; i < 8; ++i) h[i] = 0.f;
    const float* drow = &df[k * 68];
    for (int c = 0; c < 64; ++c) {
        float d = drow[c];
        const float4 w0 = *(const float4*)&wT[c * 132 + oq * 8 + 0];
        const float4 w1 = *(const float4*)&wT[c * 132 + oq * 8 + 4];
        h[0] += d * w0.x; h[1] += d * w0.y; h[2] += d * w0.z; h[3] += d * w0.w;
        h[4] += d * w1.x; h[5] += d * w1.y; h[6] += d * w1.z; h[7] += d * w1.w;
    }

#pragma unroll
    for (int i = 0; i < 8; ++i) {
        int o = oq * 8 + i;
        float v = fmaxf(h[i] * ss[o] + ss[128 + o], 0.f);
        hred[k * 132 + o] = v;
    }
    __syncthreads();

    if (t < 128) {
        float m = hred[t];
#pragma unroll
        for (int kk = 1; kk < 16; ++kk) m = fmaxf(m, hred[kk * 132 + t]);
        out[((size_t)b * NPT + n) * COUT + t] = m;
    }
}

// ---------------------------------------------------------------------------
extern "C" void kernel_launch(void* const* d_in, const int* in_sizes, int n_in,
                              void* d_out, int out_size, void* d_ws, size_t ws_size,
                              hipStream_t stream) {
    const float* x     = (const float*)d_in[0];
    const float* p     = (const float*)d_in[1];
    const float* w     = (const float*)d_in[2];
    const float* gamma = (const float*)d_in[3];
    const float* beta  = (const float*)d_in[4];

    float* out  = (float*)d_out;                               // [16,1024,128]
    float* newp = out + (size_t)B_ * NPT * COUT;               // [16,1024,3]

    char* ws = (char*)d_ws;
    int*   idx  = (int*)(ws + 0);           // 16384 ints
    int*   knn  = (int*)(ws + 65536);       // 262144 ints
    float* part = (float*)(ws + 1114112);   // 256*4160 floats
    float* M    = (float*)(ws + 5373952);   // 4160 floats
    float* st   = (float*)(ws + 5390592);   // 256 floats

    hipLaunchKernelGGL(fps_kernel,   dim3(B_),        dim3(1024), 0, stream, p, idx, newp);
    hipLaunchKernelGGL(knn_kernel,   dim3(B_ * NPT),  dim3(256),  0, stream, p, idx, knn);
    hipLaunchKernelGGL(stats_kernel, dim3(256),       dim3(256),  0, stream, x, idx, knn, part);
    hipLaunchKernelGGL(reduce_kernel,dim3(17),        dim3(256),  0, stream, part, M);
    hipLaunchKernelGGL(scale_kernel, dim3(128),       dim3(64),   0, stream, M, w, gamma, beta, st);
    hipLaunchKernelGGL(out_kernel,   dim3(B_ * NPT),  dim3(256),  0, stream, x, w, idx, knn, st, out);
}

// Round 3
// 1231.259 us; speedup vs baseline: 1.5741x; 1.0242x over previous
//
#include <hip/hip_runtime.h>

#define B_   16
#define N_   4096
#define CIN  64
#define COUT 128
#define NPT  1024
#define KNNK 16

typedef unsigned long long u64;

__device__ __forceinline__ float fINF() { return __int_as_float(0x7f800000); }

// DPP cross-lane helpers: masks {xor1=0xB1, xor2=0x4E, xor7=0x141(row_half_mirror),
// xor15=0x140(row_mirror)} generate the full 16-lane subgroup, so 4 stages give a
// 16-lane reduce at VALU speed (no DS latency).
template<int CTRL>
__device__ __forceinline__ float fmax_dpp(float v) {
    int x = __builtin_amdgcn_update_dpp(0, __float_as_int(v), CTRL, 0xF, 0xF, true);
    return fmaxf(v, __int_as_float(x));
}
template<int CTRL>
__device__ __forceinline__ float fmin_dpp(float v) {
    int x = __builtin_amdgcn_update_dpp(0, __float_as_int(v), CTRL, 0xF, 0xF, true);
    return fminf(v, __int_as_float(x));
}
template<int CTRL>
__device__ __forceinline__ u64 u64max_dpp(u64 k) {
    unsigned lo = (unsigned)k, hi = (unsigned)(k >> 32);
    unsigned plo = (unsigned)__builtin_amdgcn_update_dpp(0, (int)lo, CTRL, 0xF, 0xF, true);
    unsigned phi = (unsigned)__builtin_amdgcn_update_dpp(0, (int)hi, CTRL, 0xF, 0xF, true);
    u64 pk = ((u64)phi << 32) | plo;
    return pk > k ? pk : k;
}
template<int CTRL>
__device__ __forceinline__ u64 u64min_dpp(u64 k) {
    unsigned lo = (unsigned)k, hi = (unsigned)(k >> 32);
    unsigned plo = (unsigned)__builtin_amdgcn_update_dpp(0, (int)lo, CTRL, 0xF, 0xF, true);
    unsigned phi = (unsigned)__builtin_amdgcn_update_dpp(0, (int)hi, CTRL, 0xF, 0xF, true);
    u64 pk = ((u64)phi << 32) | plo;
    return pk < k ? pk : k;
}

// ---------------------------------------------------------------------------
// K1: FPS. 1024 threads/batch, thread t owns points 4t..4t+3 (3 aligned float4
// loads, no LDS staging). Per step: update + DPP value-max + 2 shfl stages +
// ballot/ctz argmax (lowest lane = lowest index) -> winner lane writes packed
// key + centroid coords to parity slot. ONE barrier. All waves combine 16 slots
// via DPP u64-max; next centroid coords come from the winning slot.
// ---------------------------------------------------------------------------
__global__ __launch_bounds__(1024) void fps_kernel(const float* __restrict__ p,
                                                   int* __restrict__ idx_out,
                                                   float* __restrict__ newp_out) {
    __shared__ u64   skey[2][16];
    __shared__ float scx[2][16], scy[2][16], scz[2][16];
    __shared__ int   sidx[NPT];

    const int b = blockIdx.x;
    const int t = threadIdx.x;
    const int lane = t & 63, wave = t >> 6;
    const float* pb = p + (size_t)b * N_ * 3;

    // thread t's 4 points: floats [12t, 12t+12) = float4 [3t, 3t+3)
    const float4* pb4 = (const float4*)pb;
    float4 a0 = pb4[t * 3 + 0], a1 = pb4[t * 3 + 1], a2 = pb4[t * 3 + 2];
    float lx[4], ly[4], lz[4], dist[4];
    lx[0] = a0.x; ly[0] = a0.y; lz[0] = a0.z;
    lx[1] = a0.w; ly[1] = a1.x; lz[1] = a1.y;
    lx[2] = a1.z; ly[2] = a1.w; lz[2] = a2.x;
    lx[3] = a2.y; ly[3] = a2.z; lz[3] = a2.w;
    dist[0] = dist[1] = dist[2] = dist[3] = 1e10f;

    float cx = pb[0], cy = pb[1], cz = pb[2];   // far = 0
    if (t == 0) sidx[0] = 0;

    for (int s = 1; s < NPT; ++s) {
        const int par = s & 1;
        // ---- update (exact same arithmetic as R1: passed) ----
        float nd0, nd1, nd2, nd3;
        {
            float dx, dy, dz, d;
            dx = lx[0]-cx; dy = ly[0]-cy; dz = lz[0]-cz; d = dx*dx + dy*dy + dz*dz;
            nd0 = fminf(dist[0], d); dist[0] = nd0;
            dx = lx[1]-cx; dy = ly[1]-cy; dz = lz[1]-cz; d = dx*dx + dy*dy + dz*dz;
            nd1 = fminf(dist[1], d); dist[1] = nd1;
            dx = lx[2]-cx; dy = ly[2]-cy; dz = lz[2]-cz; d = dx*dx + dy*dy + dz*dz;
            nd2 = fminf(dist[2], d); dist[2] = nd2;
            dx = lx[3]-cx; dy = ly[3]-cy; dz = lz[3]-cz; d = dx*dx + dy*dy + dz*dz;
            nd3 = fminf(dist[3], d); dist[3] = nd3;
        }
        // ---- wave value-max: 4 DPP stages + xor16 + xor32 ----
        float bv = fmaxf(fmaxf(nd0, nd1), fmaxf(nd2, nd3));
        bv = fmax_dpp<0xB1>(bv);
        bv = fmax_dpp<0x4E>(bv);
        bv = fmax_dpp<0x141>(bv);
        bv = fmax_dpp<0x140>(bv);
        bv = fmaxf(bv, __shfl_xor(bv, 16));
        bv = fmaxf(bv, __shfl_xor(bv, 32));
        // ---- argmax lane via ballot (lowest lane = lowest global index) ----
        bool m = (nd0 == bv) | (nd1 == bv) | (nd2 == bv) | (nd3 == bv);
        u64 ball = __ballot(m);
        int winlane = (int)__builtin_ctzll(ball);
        if (lane == winlane) {
            int j = (nd0 == bv) ? 0 : ((nd1 == bv) ? 1 : ((nd2 == bv) ? 2 : 3));
            int gidx = t * 4 + j;
            skey[par][wave] = ((u64)__float_as_uint(bv) << 32) | (unsigned)(~gidx);
            float wx = (j == 0) ? lx[0] : (j == 1) ? lx[1] : (j == 2) ? lx[2] : lx[3];
            float wy = (j == 0) ? ly[0] : (j == 1) ? ly[1] : (j == 2) ? ly[2] : ly[3];
            float wz = (j == 0) ? lz[0] : (j == 1) ? lz[1] : (j == 2) ? lz[2] : lz[3];
            scx[par][wave] = wx; scy[par][wave] = wy; scz[par][wave] = wz;
        }
        __syncthreads();
        // ---- combine 16 slots: DPP u64-max over 16-lane rows ----
        u64 k = skey[par][lane & 15];
        k = u64max_dpp<0xB1>(k);
        k = u64max_dpp<0x4E>(k);
        k = u64max_dpp<0x141>(k);
        k = u64max_dpp<0x140>(k);
        int widx = (int)(~(unsigned)(k & 0xFFFFFFFFull));
        int wwave = widx >> 8;
        cx = scx[par][wwave]; cy = scy[par][wwave]; cz = scz[par][wwave];
        if (t == 0) sidx[s] = widx;
    }
    __syncthreads();

    {
        int i = sidx[t];
        idx_out[b * NPT + t] = i;
        float* np = newp_out + ((size_t)b * NPT + t) * 3;
        np[0] = pb[3 * i + 0]; np[1] = pb[3 * i + 1]; np[2] = pb[3 * i + 2];
    }
}

// ---------------------------------------------------------------------------
// K2: KNN. 256 thr/query, thread t owns points 16t..16t+15 (12 float4 loads).
// 17 extraction rounds, each: DPP value-min + ballot tie-break + packed-key
// cross-wave min (4 slots, 2 DPP stages). ONE barrier/round. Tie semantics
// identical to lax.top_k (min value, then min index).
// ---------------------------------------------------------------------------
__global__ __launch_bounds__(256) void knn_kernel(const float* __restrict__ p,
                                                  const int* __restrict__ idx_in,
                                                  int* __restrict__ knn_out) {
    __shared__ u64 skey[2][4];

    const int blk = blockIdx.x;
    const int b = blk >> 10, n = blk & 1023;
    const int t = threadIdx.x;
    const int lane = t & 63, wave = t >> 6;
    const float* pb = p + (size_t)b * N_ * 3;

    const int qi = idx_in[b * NPT + n];
    const float qx = pb[qi * 3 + 0], qy = pb[qi * 3 + 1], qz = pb[qi * 3 + 2];

    // 16 points = 48 floats = 12 aligned float4
    float fl[48];
    const float4* pb4 = (const float4*)pb;
#pragma unroll
    for (int i = 0; i < 12; ++i) {
        float4 v = pb4[t * 12 + i];
        fl[4 * i + 0] = v.x; fl[4 * i + 1] = v.y; fl[4 * i + 2] = v.z; fl[4 * i + 3] = v.w;
    }
    float dist[16];
#pragma unroll
    for (int j = 0; j < 16; ++j) {
        float dx = fl[3 * j + 0] - qx;
        float dy = fl[3 * j + 1] - qy;
        float dz = fl[3 * j + 2] - qz;
        dist[j] = dx * dx + dy * dy + dz * dz;
    }

    float lmin;
    {
        float m0 = fminf(fminf(dist[0], dist[1]), fminf(dist[2], dist[3]));
        float m1 = fminf(fminf(dist[4], dist[5]), fminf(dist[6], dist[7]));
        float m2 = fminf(fminf(dist[8], dist[9]), fminf(dist[10], dist[11]));
        float m3 = fminf(fminf(dist[12], dist[13]), fminf(dist[14], dist[15]));
        lmin = fminf(fminf(m0, m1), fminf(m2, m3));
    }

    int* kout = knn_out + ((size_t)b * NPT + n) * KNNK;

    for (int r = 0; r < 17; ++r) {
        const int par = r & 1;
        float wv = lmin;
        wv = fmin_dpp<0xB1>(wv);
        wv = fmin_dpp<0x4E>(wv);
        wv = fmin_dpp<0x141>(wv);
        wv = fmin_dpp<0x140>(wv);
        wv = fminf(wv, __shfl_xor(wv, 16));
        wv = fminf(wv, __shfl_xor(wv, 32));
        u64 ball = __ballot(lmin == wv);
        int winlane = (int)__builtin_ctzll(ball);
        if (lane == winlane) {
            int j = 15;
#pragma unroll
            for (int jj = 15; jj >= 0; --jj)
                if (dist[jj] == wv) j = jj;          // lowest matching j
            skey[par][wave] = ((u64)__float_as_uint(wv) << 32) | (unsigned)(t * 16 + j);
        }
        __syncthreads();
        u64 k = skey[par][lane & 3];
        k = u64min_dpp<0xB1>(k);
        k = u64min_dpp<0x4E>(k);
        const int widx = (int)(unsigned)(k & 0xFFFFFFFFull);
        if (t == 0 && r > 0) kout[r - 1] = widx;
        if ((widx >> 4) == t) {
#pragma unroll
            for (int jj = 0; jj < 16; ++jj)
                if ((widx & 15) == jj) dist[jj] = fINF();
            float m0 = fminf(fminf(dist[0], dist[1]), fminf(dist[2], dist[3]));
            float m1 = fminf(fminf(dist[4], dist[5]), fminf(dist[6], dist[7]));
            float m2 = fminf(fminf(dist[8], dist[9]), fminf(dist[10], dist[11]));
            float m3 = fminf(fminf(dist[12], dist[13]), fminf(dist[14], dist[15]));
            lmin = fminf(fminf(m0, m1), fminf(m2, m3));
        }
    }
}

// ---------------------------------------------------------------------------
// K3: second-moment stats (unchanged: mean_o = w_o.E[d], E[h_o^2] = w_o^T E[dd^T] w_o)
// ---------------------------------------------------------------------------
__global__ __launch_bounds__(256) void stats_kernel(const float* __restrict__ x,
                                                    const int* __restrict__ idx_in,
                                                    const int* __restrict__ knn_in,
                                                    float* __restrict__ part) {
    __shared__ float xc[4 * 64];
    __shared__ float dls[64 * 72];

    const int blk = blockIdx.x;
    const int t = threadIdx.x;
    const int q0 = blk * 64;
    const int b = q0 >> 10;
    const float* xb = x + (size_t)b * N_ * CIN;

    float acc[4][4];
#pragma unroll
    for (int i = 0; i < 4; ++i)
#pragma unroll
        for (int j = 0; j < 4; ++j) acc[i][j] = 0.f;
    float dsum = 0.f;

    const int r0 = (t >> 4) * 4, c0 = (t & 15) * 4;

    for (int sg = 0; sg < 16; ++sg) {
        __syncthreads();
        {
            int qq = t >> 6, c = t & 63;
            int q = q0 + sg * 4 + qq;
            int ci = idx_in[q];
            xc[qq * 64 + c] = xb[ci * CIN + c];
        }
        __syncthreads();
        for (int i = 0; i < 16; ++i) {
            int f = t + 256 * i;
            int qq = f >> 10, k = (f >> 6) & 15, c = f & 63;
            int q = q0 + sg * 4 + qq;
            int row = knn_in[q * KNNK + k];
            dls[(qq * 16 + k) * 72 + c] = xc[qq * 64 + c] - xb[row * CIN + c];
        }
        __syncthreads();
#pragma unroll 4
        for (int s = 0; s < 64; ++s) {
            const float4 a  = *(const float4*)&dls[s * 72 + r0];
            const float4 bb = *(const float4*)&dls[s * 72 + c0];
            acc[0][0] += a.x * bb.x; acc[0][1] += a.x * bb.y; acc[0][2] += a.x * bb.z; acc[0][3] += a.x * bb.w;
            acc[1][0] += a.y * bb.x; acc[1][1] += a.y * bb.y; acc[1][2] += a.y * bb.z; acc[1][3] += a.y * bb.w;
            acc[2][0] += a.z * bb.x; acc[2][1] += a.z * bb.y; acc[2][2] += a.z * bb.z; acc[2][3] += a.z * bb.w;
            acc[3][0] += a.w * bb.x; acc[3][1] += a.w * bb.y; acc[3][2] += a.w * bb.z; acc[3][3] += a.w * bb.w;
        }
        if (t < 64) {
            for (int s = 0; s < 64; ++s) dsum += dls[s * 72 + t];
        }
    }

    float* pout = part + (size_t)blk * 4160;
#pragma unroll
    for (int i = 0; i < 4; ++i)
#pragma unroll
        for (int j = 0; j < 4; ++j)
            pout[(r0 + i) * 64 + (c0 + j)] = acc[i][j];
    if (t < 64) pout[4096 + t] = dsum;
}

__global__ __launch_bounds__(256) void reduce_kernel(const float* __restrict__ part,
                                                     float* __restrict__ M) {
    int e = blockIdx.x * 256 + threadIdx.x;
    if (e >= 4160) return;
    float s = 0.f;
    for (int b = 0; b < 256; ++b) s += part[(size_t)b * 4160 + e];
    M[e] = s;
}

__global__ __launch_bounds__(64) void scale_kernel(const float* __restrict__ M,
                                                   const float* __restrict__ w,
                                                   const float* __restrict__ gamma,
                                                   const float* __restrict__ beta,
                                                   float* __restrict__ st) {
    __shared__ float wv[64];
    const int o = blockIdx.x, t = threadIdx.x;
    wv[t] = w[o * 64 + t];
    __syncthreads();
    const float* Mr = M + t * 64;
    float sr = 0.f;
    for (int c = 0; c < 64; ++c) sr += Mr[c] * wv[c];
    float e2 = wv[t] * sr;
    float mn = wv[t] * M[4096 + t];
#pragma unroll
    for (int off = 32; off >= 1; off >>= 1) {
        e2 += __shfl_xor(e2, off);
        mn += __shfl_xor(mn, off);
    }
    if (t == 0) {
        const float Ns = 262144.0f;
        float mean = mn / Ns;
        float var = e2 / Ns - mean * mean;
        float scale = gamma[o] * rsqrtf(var + 1e-5f);
        st[o] = scale;
        st[128 + o] = beta[o] - mean * scale;
    }
}

// ---------------------------------------------------------------------------
// K5: fused output. 4 queries/block (register-blocked: 32 fma per 48B LDS read,
// was 8 per 36B -> LDS-pipe-bound). Epilogue: affine+relu then DPP max over the
// 16 k-lanes (exact same float result as LDS-tree max; removes hred + barrier).
// ---------------------------------------------------------------------------
__global__ __launch_bounds__(256) void out_kernel(const float* __restrict__ x,
                                                  const float* __restrict__ w,
                                                  const int* __restrict__ idx_in,
                                                  const int* __restrict__ knn_in,
                                                  const float* __restrict__ st,
                                                  float* __restrict__ out) {
    __shared__ float wT[64 * 132];        // wT[c][o]
    __shared__ float ss[256];
    __shared__ float df4[16 * 260];       // df4[k*260 + c*4 + q]  (k-stride 260: 2-way banks)
    __shared__ int   skr[64];
    __shared__ int   sci[4];

    const int blk = blockIdx.x;           // 4096 blocks
    const int b = blk >> 8, n0 = (blk & 255) * 4;
    const int t = threadIdx.x;
    const float* xb = x + (size_t)b * N_ * CIN;

    for (int i = 0; i < 32; ++i) {        // coalesced w load, transposed store
        int f = t + 256 * i;
        int o = f >> 6, c = f & 63;
        wT[c * 132 + o] = w[f];
    }
    ss[t] = st[t];
    if (t < 64) skr[t] = knn_in[((size_t)b * NPT + n0) * KNNK + t];
    if (t < 4)  sci[t] = idx_in[b * NPT + n0 + t];
    __syncthreads();

    // stage diffs for 4 queries: iter i covers k=i; c=t>>2, q=t&3
    for (int i = 0; i < 16; ++i) {
        int c = t >> 2, q = t & 3;
        int center = sci[q];
        int row = skr[q * 16 + i];
        df4[i * 260 + c * 4 + q] = xb[center * CIN + c] - xb[row * CIN + c];
    }
    __syncthreads();

    const int k = t & 15, oq = t >> 4;    // 16 k x 16 o-groups of 8
    float acc[4][8];
#pragma unroll
    for (int q = 0; q < 4; ++q)
#pragma unroll
        for (int i = 0; i < 8; ++i) acc[q][i] = 0.f;

    const float* dr = &df4[k * 260];
    for (int c = 0; c < 64; ++c) {
        const float4 d4 = *(const float4*)&dr[c * 4];
        const float4 w0 = *(const float4*)&wT[c * 132 + oq * 8 + 0];
        const float4 w1 = *(const float4*)&wT[c * 132 + oq * 8 + 4];
        float dv[4] = {d4.x, d4.y, d4.z, d4.w};
        float wvv[8] = {w0.x, w0.y, w0.z, w0.w, w1.x, w1.y, w1.z, w1.w};
#pragma unroll
        for (int q = 0; q < 4; ++q)
#pragma unroll
            for (int i = 0; i < 8; ++i) acc[q][i] += dv[q] * wvv[i];
    }

    // affine + relu, then max over k (16 lanes) via DPP; lane k==0 stores
#pragma unroll
    for (int q = 0; q < 4; ++q)
#pragma unroll
        for (int i = 0; i < 8; ++i) {
            int o = oq * 8 + i;
            float v = fmaxf(acc[q][i] * ss[o] + ss[128 + o], 0.f);
            v = fmax_dpp<0xB1>(v);
            v = fmax_dpp<0x4E>(v);
            v = fmax_dpp<0x141>(v);
            v = fmax_dpp<0x140>(v);
            acc[q][i] = v;
        }
    if (k == 0) {
#pragma unroll
        for (int q = 0; q < 4; ++q) {
            float4 o0 = {acc[q][0], acc[q][1], acc[q][2], acc[q][3]};
            float4 o1 = {acc[q][4], acc[q][5], acc[q][6], acc[q][7]};
            float* op = out + ((size_t)b * NPT + n0 + q) * COUT + oq * 8;
            *(float4*)&op[0] = o0;
            *(float4*)&op[4] = o1;
        }
    }
}

// ---------------------------------------------------------------------------
extern "C" void kernel_launch(void* const* d_in, const int* in_sizes, int n_in,
                              void* d_out, int out_size, void* d_ws, size_t ws_size,
                              hipStream_t stream) {
    const float* x     = (const float*)d_in[0];
    const float* p     = (const float*)d_in[1];
    const float* w     = (const float*)d_in[2];
    const float* gamma = (const float*)d_in[3];
    const float* beta  = (const float*)d_in[4];

    float* out  = (float*)d_out;                               // [16,1024,128]
    float* newp = out + (size_t)B_ * NPT * COUT;               // [16,1024,3]

    char* ws = (char*)d_ws;
    int*   idx  = (int*)(ws + 0);           // 16384 ints
    int*   knn  = (int*)(ws + 65536);       // 262144 ints
    float* part = (float*)(ws + 1114112);   // 256*4160 floats
    float* M    = (float*)(ws + 5373952);   // 4160 floats
    float* st   = (float*)(ws + 5390592);   // 256 floats

    hipLaunchKernelGGL(fps_kernel,   dim3(B_),          dim3(1024), 0, stream, p, idx, newp);
    hipLaunchKernelGGL(knn_kernel,   dim3(B_ * NPT),    dim3(256),  0, stream, p, idx, knn);
    hipLaunchKernelGGL(stats_kernel, dim3(256),         dim3(256),  0, stream, x, idx, knn, part);
    hipLaunchKernelGGL(reduce_kernel,dim3(17),          dim3(256),  0, stream, part, M);
    hipLaunchKernelGGL(scale_kernel, dim3(128),         dim3(64),   0, stream, M, w, gamma, beta, st);
    hipLaunchKernelGGL(out_kernel,   dim3(B_ * NPT/4),  dim3(256),  0, stream, x, w, idx, knn, st, out);
}

// Round 5
// 1135.751 us; speedup vs baseline: 1.7065x; 1.0841x over previous
//
#include <hip/hip_runtime.h>

#define B_   16
#define N_   4096
#define CIN  64
#define COUT 128
#define NPT  1024
#define KNNK 16

typedef unsigned long long u64;

__device__ __forceinline__ float fINF() { return __int_as_float(0x7f800000); }

// DPP cross-lane helpers: masks {xor1=0xB1, xor2=0x4E, half_mirror=0x141,
// mirror=0x140} generate the 16-lane subgroup at VALU speed (no DS latency).
template<int CTRL>
__device__ __forceinline__ float fmax_dpp(float v) {
    int x = __builtin_amdgcn_update_dpp(0, __float_as_int(v), CTRL, 0xF, 0xF, true);
    return fmaxf(v, __int_as_float(x));
}
template<int CTRL>
__device__ __forceinline__ float fmin_dpp(float v) {
    int x = __builtin_amdgcn_update_dpp(0, __float_as_int(v), CTRL, 0xF, 0xF, true);
    return fminf(v, __int_as_float(x));
}
template<int CTRL>
__device__ __forceinline__ u64 u64min_dpp(u64 k) {
    unsigned lo = (unsigned)k, hi = (unsigned)(k >> 32);
    unsigned plo = (unsigned)__builtin_amdgcn_update_dpp(0, (int)lo, CTRL, 0xF, 0xF, true);
    unsigned phi = (unsigned)__builtin_amdgcn_update_dpp(0, (int)hi, CTRL, 0xF, 0xF, true);
    u64 pk = ((u64)phi << 32) | plo;
    return pk < k ? pk : k;
}

// ---------------------------------------------------------------------------
// K1: FPS, two-phase argmax. 1024 thr/batch, 4 pts/thread in registers.
// Phase A (per wave): update + value-only full-wave max, lane0 publishes the
// wave max (2 instrs). Phase B (all waves): 1 LDS read + 4 DPP fmax + ballot
// -> winning wave; ONLY that wave (uniform branch) re-derives winner lane/j
// and writes {x,y,z,idx} as one float4. Second barrier, all read the slot.
// Winner-extraction amortized 16x vs R2. Tie order: lowest wave -> lowest
// lane -> lowest j == lowest global index == jnp.argmax semantics.
// ---------------------------------------------------------------------------
__global__ __launch_bounds__(1024) void fps_kernel(const float* __restrict__ p,
                                                   int* __restrict__ idx_out,
                                                   float* __restrict__ newp_out) {
    __shared__ float  sval[2][16];
    __shared__ float4 sres[2];
    __shared__ int    sidx[NPT];

    const int b = blockIdx.x;
    const int t = threadIdx.x;
    const int lane = t & 63, wave = t >> 6;
    const float* pb = p + (size_t)b * N_ * 3;

    // thread t's 4 points: floats [12t, 12t+12) = float4 [3t, 3t+3)
    const float4* pb4 = (const float4*)pb;
    float4 a0 = pb4[t * 3 + 0], a1 = pb4[t * 3 + 1], a2 = pb4[t * 3 + 2];
    float lx[4], ly[4], lz[4], dist[4];
    lx[0] = a0.x; ly[0] = a0.y; lz[0] = a0.z;
    lx[1] = a0.w; ly[1] = a1.x; lz[1] = a1.y;
    lx[2] = a1.z; ly[2] = a1.w; lz[2] = a2.x;
    lx[3] = a2.y; ly[3] = a2.z; lz[3] = a2.w;
    dist[0] = dist[1] = dist[2] = dist[3] = 1e10f;

    float cx = pb[0], cy = pb[1], cz = pb[2];   // far = 0
    if (t == 0) sidx[0] = 0;

    for (int s = 1; s < NPT; ++s) {
        const int par = s & 1;
        // ---- phase A: update (exact same arithmetic as R1/R2: passed) ----
        float nd0, nd1, nd2, nd3;
        {
            float dx, dy, dz, d;
            dx = lx[0]-cx; dy = ly[0]-cy; dz = lz[0]-cz; d = dx*dx + dy*dy + dz*dz;
            nd0 = fminf(dist[0], d); dist[0] = nd0;
            dx = lx[1]-cx; dy = ly[1]-cy; dz = lz[1]-cz; d = dx*dx + dy*dy + dz*dz;
            nd1 = fminf(dist[1], d); dist[1] = nd1;
            dx = lx[2]-cx; dy = ly[2]-cy; dz = lz[2]-cz; d = dx*dx + dy*dy + dz*dz;
            nd2 = fminf(dist[2], d); dist[2] = nd2;
            dx = lx[3]-cx; dy = ly[3]-cy; dz = lz[3]-cz; d = dx*dx + dy*dy + dz*dz;
            nd3 = fminf(dist[3], d); dist[3] = nd3;
        }
        float bv = fmaxf(fmaxf(nd0, nd1), fmaxf(nd2, nd3));
        bv = fmax_dpp<0xB1>(bv);
        bv = fmax_dpp<0x4E>(bv);
        bv = fmax_dpp<0x141>(bv);
        bv = fmax_dpp<0x140>(bv);
        bv = fmaxf(bv, __shfl_xor(bv, 16));
        bv = fmaxf(bv, __shfl_xor(bv, 32));
        if (lane == 0) sval[par][wave] = bv;
        __syncthreads();
        // ---- phase B: pick winning wave (all), extract winner (1 wave) ----
        float v = sval[par][lane & 15];
        float gmax = v;
        gmax = fmax_dpp<0xB1>(gmax);
        gmax = fmax_dpp<0x4E>(gmax);
        gmax = fmax_dpp<0x141>(gmax);
        gmax = fmax_dpp<0x140>(gmax);
        u64 ball = __ballot(v == gmax);
        int wwave = (int)__builtin_ctzll(ball);    // lanes 0..15 cover slots in order
        if (wave == wwave) {                        // wave-uniform: 15 waves skip
            bool m = (nd0 == bv) | (nd1 == bv) | (nd2 == bv) | (nd3 == bv);
            u64 b2 = __ballot(m);
            int winlane = (int)__builtin_ctzll(b2);
            if (lane == winlane) {
                int j = (nd0 == bv) ? 0 : ((nd1 == bv) ? 1 : ((nd2 == bv) ? 2 : 3));
                float wx = (j == 0) ? lx[0] : (j == 1) ? lx[1] : (j == 2) ? lx[2] : lx[3];
                float wy = (j == 0) ? ly[0] : (j == 1) ? ly[1] : (j == 2) ? ly[2] : ly[3];
                float wz = (j == 0) ? lz[0] : (j == 1) ? lz[1] : (j == 2) ? lz[2] : lz[3];
                float4 r; r.x = wx; r.y = wy; r.z = wz; r.w = __int_as_float(t * 4 + j);
                sres[par] = r;
            }
        }
        __syncthreads();
        float4 r = sres[par];
        cx = r.x; cy = r.y; cz = r.z;
        if (t == 0) sidx[s] = __float_as_int(r.w);
    }
    __syncthreads();

    {
        int i = sidx[t];
        idx_out[b * NPT + t] = i;
        float* np = newp_out + ((size_t)b * NPT + t) * 3;
        np[0] = pb[3 * i + 0]; np[1] = pb[3 * i + 1]; np[2] = pb[3 * i + 2];
    }
}

// ---------------------------------------------------------------------------
// K2: KNN. 256 thr/query, thread t owns points 16t..16t+15. 17 extraction
// rounds. The removal/rescan block is guarded wave-uniformly
// ((widx>>10)==wave) so 3 of 4 waves branch over its ~45 instrs.
// ---------------------------------------------------------------------------
__global__ __launch_bounds__(256) void knn_kernel(const float* __restrict__ p,
                                                  const int* __restrict__ idx_in,
                                                  int* __restrict__ knn_out) {
    __shared__ u64 skey[2][4];

    const int blk = blockIdx.x;
    const int b = blk >> 10, n = blk & 1023;
    const int t = threadIdx.x;
    const int lane = t & 63, wave = t >> 6;
    const float* pb = p + (size_t)b * N_ * 3;

    const int qi = idx_in[b * NPT + n];
    const float qx = pb[qi * 3 + 0], qy = pb[qi * 3 + 1], qz = pb[qi * 3 + 2];

    float fl[48];
    const float4* pb4 = (const float4*)pb;
#pragma unroll
    for (int i = 0; i < 12; ++i) {
        float4 v = pb4[t * 12 + i];
        fl[4 * i + 0] = v.x; fl[4 * i + 1] = v.y; fl[4 * i + 2] = v.z; fl[4 * i + 3] = v.w;
    }
    float dist[16];
#pragma unroll
    for (int j = 0; j < 16; ++j) {
        float dx = fl[3 * j + 0] - qx;
        float dy = fl[3 * j + 1] - qy;
        float dz = fl[3 * j + 2] - qz;
        dist[j] = dx * dx + dy * dy + dz * dz;
    }

    float lmin;
    {
        float m0 = fminf(fminf(dist[0], dist[1]), fminf(dist[2], dist[3]));
        float m1 = fminf(fminf(dist[4], dist[5]), fminf(dist[6], dist[7]));
        float m2 = fminf(fminf(dist[8], dist[9]), fminf(dist[10], dist[11]));
        float m3 = fminf(fminf(dist[12], dist[13]), fminf(dist[14], dist[15]));
        lmin = fminf(fminf(m0, m1), fminf(m2, m3));
    }

    int* kout = knn_out + ((size_t)b * NPT + n) * KNNK;

    for (int r = 0; r < 17; ++r) {
        const int par = r & 1;
        float wv = lmin;
        wv = fmin_dpp<0xB1>(wv);
        wv = fmin_dpp<0x4E>(wv);
        wv = fmin_dpp<0x141>(wv);
        wv = fmin_dpp<0x140>(wv);
        wv = fminf(wv, __shfl_xor(wv, 16));
        wv = fminf(wv, __shfl_xor(wv, 32));
        u64 ball = __ballot(lmin == wv);
        int winlane = (int)__builtin_ctzll(ball);
        if (lane == winlane) {
            int j = 15;
#pragma unroll
            for (int jj = 15; jj >= 0; --jj)
                if (dist[jj] == wv) j = jj;          // lowest matching j
            skey[par][wave] = ((u64)__float_as_uint(wv) << 32) | (unsigned)(t * 16 + j);
        }
        __syncthreads();
        u64 k = skey[par][lane & 3];
        k = u64min_dpp<0xB1>(k);
        k = u64min_dpp<0x4E>(k);
        const int widx = (int)(unsigned)(k & 0xFFFFFFFFull);
        if (t == 0 && r > 0) kout[r - 1] = widx;
        if ((widx >> 10) == wave) {                  // wave-uniform guard
            if ((widx >> 4) == t) {
#pragma unroll
                for (int jj = 0; jj < 16; ++jj)
                    if ((widx & 15) == jj) dist[jj] = fINF();
                float m0 = fminf(fminf(dist[0], dist[1]), fminf(dist[2], dist[3]));
                float m1 = fminf(fminf(dist[4], dist[5]), fminf(dist[6], dist[7]));
                float m2 = fminf(fminf(dist[8], dist[9]), fminf(dist[10], dist[11]));
                float m3 = fminf(fminf(dist[12], dist[13]), fminf(dist[14], dist[15]));
                lmin = fminf(fminf(m0, m1), fminf(m2, m3));
            }
        }
    }
}

// ---------------------------------------------------------------------------
// K3: second-moment stats (unchanged)
// ---------------------------------------------------------------------------
__global__ __launch_bounds__(256) void stats_kernel(const float* __restrict__ x,
                                                    const int* __restrict__ idx_in,
                                                    const int* __restrict__ knn_in,
                                                    float* __restrict__ part) {
    __shared__ float xc[4 * 64];
    __shared__ float dls[64 * 72];

    const int blk = blockIdx.x;
    const int t = threadIdx.x;
    const int q0 = blk * 64;
    const int b = q0 >> 10;
    const float* xb = x + (size_t)b * N_ * CIN;

    float acc[4][4];
#pragma unroll
    for (int i = 0; i < 4; ++i)
#pragma unroll
        for (int j = 0; j < 4; ++j) acc[i][j] = 0.f;
    float dsum = 0.f;

    const int r0 = (t >> 4) * 4, c0 = (t & 15) * 4;

    for (int sg = 0; sg < 16; ++sg) {
        __syncthreads();
        {
            int qq = t >> 6, c = t & 63;
            int q = q0 + sg * 4 + qq;
            int ci = idx_in[q];
            xc[qq * 64 + c] = xb[ci * CIN + c];
        }
        __syncthreads();
        for (int i = 0; i < 16; ++i) {
            int f = t + 256 * i;
            int qq = f >> 10, k = (f >> 6) & 15, c = f & 63;
            int q = q0 + sg * 4 + qq;
            int row = knn_in[q * KNNK + k];
            dls[(qq * 16 + k) * 72 + c] = xc[qq * 64 + c] - xb[row * CIN + c];
        }
        __syncthreads();
#pragma unroll 4
        for (int s = 0; s < 64; ++s) {
            const float4 a  = *(const float4*)&dls[s * 72 + r0];
            const float4 bb = *(const float4*)&dls[s * 72 + c0];
            acc[0][0] += a.x * bb.x; acc[0][1] += a.x * bb.y; acc[0][2] += a.x * bb.z; acc[0][3] += a.x * bb.w;
            acc[1][0] += a.y * bb.x; acc[1][1] += a.y * bb.y; acc[1][2] += a.y * bb.z; acc[1][3] += a.y * bb.w;
            acc[2][0] += a.z * bb.x; acc[2][1] += a.z * bb.y; acc[2][2] += a.z * bb.z; acc[2][3] += a.z * bb.w;
            acc[3][0] += a.w * bb.x; acc[3][1] += a.w * bb.y; acc[3][2] += a.w * bb.z; acc[3][3] += a.w * bb.w;
        }
        if (t < 64) {
            for (int s = 0; s < 64; ++s) dsum += dls[s * 72 + t];
        }
    }

    float* pout = part + (size_t)blk * 4160;
#pragma unroll
    for (int i = 0; i < 4; ++i)
#pragma unroll
        for (int j = 0; j < 4; ++j)
            pout[(r0 + i) * 64 + (c0 + j)] = acc[i][j];
    if (t < 64) pout[4096 + t] = dsum;
}

__global__ __launch_bounds__(256) void reduce_kernel(const float* __restrict__ part,
                                                     float* __restrict__ M) {
    int e = blockIdx.x * 256 + threadIdx.x;
    if (e >= 4160) return;
    float s = 0.f;
    for (int b = 0; b < 256; ++b) s += part[(size_t)b * 4160 + e];
    M[e] = s;
}

__global__ __launch_bounds__(64) void scale_kernel(const float* __restrict__ M,
                                                   const float* __restrict__ w,
                                                   const float* __restrict__ gamma,
                                                   const float* __restrict__ beta,
                                                   float* __restrict__ st) {
    __shared__ float wv[64];
    const int o = blockIdx.x, t = threadIdx.x;
    wv[t] = w[o * 64 + t];
    __syncthreads();
    const float* Mr = M + t * 64;
    float sr = 0.f;
    for (int c = 0; c < 64; ++c) sr += Mr[c] * wv[c];
    float e2 = wv[t] * sr;
    float mn = wv[t] * M[4096 + t];
#pragma unroll
    for (int off = 32; off >= 1; off >>= 1) {
        e2 += __shfl_xor(e2, off);
        mn += __shfl_xor(mn, off);
    }
    if (t == 0) {
        const float Ns = 262144.0f;
        float mean = mn / Ns;
        float var = e2 / Ns - mean * mean;
        float scale = gamma[o] * rsqrtf(var + 1e-5f);
        st[o] = scale;
        st[128 + o] = beta[o] - mean * scale;
    }
}

// ---------------------------------------------------------------------------
// K5: fused output (unchanged from R2)
// ---------------------------------------------------------------------------
__global__ __launch_bounds__(256) void out_kernel(const float* __restrict__ x,
                                                  const float* __restrict__ w,
                                                  const int* __restrict__ idx_in,
                                                  const int* __restrict__ knn_in,
                                                  const float* __restrict__ st,
                                                  float* __restrict__ out) {
    __shared__ float wT[64 * 132];        // wT[c][o]
    __shared__ float ss[256];
    __shared__ float df4[16 * 260];       // df4[k*260 + c*4 + q]
    __shared__ int   skr[64];
    __shared__ int   sci[4];

    const int blk = blockIdx.x;           // 4096 blocks
    const int b = blk >> 8, n0 = (blk & 255) * 4;
    const int t = threadIdx.x;
    const float* xb = x + (size_t)b * N_ * CIN;

    for (int i = 0; i < 32; ++i) {
        int f = t + 256 * i;
        int o = f >> 6, c = f & 63;
        wT[c * 132 + o] = w[f];
    }
    ss[t] = st[t];
    if (t < 64) skr[t] = knn_in[((size_t)b * NPT + n0) * KNNK + t];
    if (t < 4)  sci[t] = idx_in[b * NPT + n0 + t];
    __syncthreads();

    for (int i = 0; i < 16; ++i) {
        int c = t >> 2, q = t & 3;
        int center = sci[q];
        int row = skr[q * 16 + i];
        df4[i * 260 + c * 4 + q] = xb[center * CIN + c] - xb[row * CIN + c];
    }
    __syncthreads();

    const int k = t & 15, oq = t >> 4;
    float acc[4][8];
#pragma unroll
    for (int q = 0; q < 4; ++q)
#pragma unroll
        for (int i = 0; i < 8; ++i) acc[q][i] = 0.f;

    const float* dr = &df4[k * 260];
    for (int c = 0; c < 64; ++c) {
        const float4 d4 = *(const float4*)&dr[c * 4];
        const float4 w0 = *(const float4*)&wT[c * 132 + oq * 8 + 0];
        const float4 w1 = *(const float4*)&wT[c * 132 + oq * 8 + 4];
        float dv[4] = {d4.x, d4.y, d4.z, d4.w};
        float wvv[8] = {w0.x, w0.y, w0.z, w0.w, w1.x, w1.y, w1.z, w1.w};
#pragma unroll
        for (int q = 0; q < 4; ++q)
#pragma unroll
            for (int i = 0; i < 8; ++i) acc[q][i] += dv[q] * wvv[i];
    }

#pragma unroll
    for (int q = 0; q < 4; ++q)
#pragma unroll
        for (int i = 0; i < 8; ++i) {
            int o = oq * 8 + i;
            float v = fmaxf(acc[q][i] * ss[o] + ss[128 + o], 0.f);
            v = fmax_dpp<0xB1>(v);
            v = fmax_dpp<0x4E>(v);
            v = fmax_dpp<0x141>(v);
            v = fmax_dpp<0x140>(v);
            acc[q][i] = v;
        }
    if (k == 0) {
#pragma unroll
        for (int q = 0; q < 4; ++q) {
            float4 o0 = {acc[q][0], acc[q][1], acc[q][2], acc[q][3]};
            float4 o1 = {acc[q][4], acc[q][5], acc[q][6], acc[q][7]};
            float* op = out + ((size_t)b * NPT + n0 + q) * COUT + oq * 8;
            *(float4*)&op[0] = o0;
            *(float4*)&op[4] = o1;
        }
    }
}

// ---------------------------------------------------------------------------
extern "C" void kernel_launch(void* const* d_in, const int* in_sizes, int n_in,
                              void* d_out, int out_size, void* d_ws, size_t ws_size,
                              hipStream_t stream) {
    const float* x     = (const float*)d_in[0];
    const float* p     = (const float*)d_in[1];
    const float* w     = (const float*)d_in[2];
    const float* gamma = (const float*)d_in[3];
    const float* beta  = (const float*)d_in[4];

    float* out  = (float*)d_out;                               // [16,1024,128]
    float* newp = out + (size_t)B_ * NPT * COUT;               // [16,1024,3]

    char* ws = (char*)d_ws;
    int*   idx  = (int*)(ws + 0);           // 16384 ints
    int*   knn  = (int*)(ws + 65536);       // 262144 ints
    float* part = (float*)(ws + 1114112);   // 256*4160 floats
    float* M    = (float*)(ws + 5373952);   // 4160 floats
    float* st   = (float*)(ws + 5390592);   // 256 floats

    hipLaunchKernelGGL(fps_kernel,   dim3(B_),          dim3(1024), 0, stream, p, idx, newp);
    hipLaunchKernelGGL(knn_kernel,   dim3(B_ * NPT),    dim3(256),  0, stream, p, idx, knn);
    hipLaunchKernelGGL(stats_kernel, dim3(256),         dim3(256),  0, stream, x, idx, knn, part);
    hipLaunchKernelGGL(reduce_kernel,dim3(17),          dim3(256),  0, stream, part, M);
    hipLaunchKernelGGL(scale_kernel, dim3(128),         dim3(64),   0, stream, M, w, gamma, beta, st);
    hipLaunchKernelGGL(out_kernel,   dim3(B_ * NPT/4),  dim3(256),  0, stream, x, w, idx, knn, st, out);
}

// Round 6
// 1051.314 us; speedup vs baseline: 1.8435x; 1.0803x over previous
//
#include <hip/hip_runtime.h>

#define B_   16
#define N_   4096
#define CIN  64
#define COUT 128
#define NPT  1024
#define KNNK 16

typedef unsigned long long u64;

__device__ __forceinline__ float fINF() { return __int_as_float(0x7f800000); }

// DPP cross-lane helpers: {xor1=0xB1, xor2=0x4E, half_mirror(rev8)=0x141,
// mirror(rev16)=0x140} at VALU speed (no DS latency).
template<int CTRL>
__device__ __forceinline__ float fmax_dpp(float v) {
    int x = __builtin_amdgcn_update_dpp(0, __float_as_int(v), CTRL, 0xF, 0xF, true);
    return fmaxf(v, __int_as_float(x));
}
template<int CTRL>
__device__ __forceinline__ float fmin_dpp(float v) {
    int x = __builtin_amdgcn_update_dpp(0, __float_as_int(v), CTRL, 0xF, 0xF, true);
    return fminf(v, __int_as_float(x));
}

// ---------------------------------------------------------------------------
// K1: FPS. 512 thr/batch (8 waves), 8 pts/thread in registers. ONE barrier
// per step. Phase A: update + value-only wave max (4 DPP + 2 shfl) + ballot
// -> winner lane writes packed {val_bits, idx} u64 slot (no index chains).
// Phase B: all waves read 8 slots, 3-stage float DPP max + ballot -> winning
// slot; widx = shfl(lo-word, winslot); coords from LDS SoA table (broadcast).
// Tie order: lowest slot(=wave) -> lowest lane -> lowest j == lowest global
// index == jnp.argmax semantics (ownership is contiguous at every level).
// ---------------------------------------------------------------------------
__global__ __launch_bounds__(512) void fps_kernel(const float* __restrict__ p,
                                                  int* __restrict__ idx_out,
                                                  float* __restrict__ newp_out) {
    __shared__ float sx[N_], sy[N_], sz[N_];
    __shared__ int   sidx[NPT];
    __shared__ u64   slot[2][8];

    const int b = blockIdx.x;
    const int t = threadIdx.x;
    const int lane = t & 63;
    const int wave = t >> 6;
    const float* pb = p + (size_t)b * N_ * 3;

    // coalesced SoA staging (coord lookup table)
    for (int i = 0; i < 24; ++i) {
        int f = t + 512 * i;
        float v = pb[f];
        int pt = f / 3, c = f - pt * 3;
        if (c == 0) sx[pt] = v; else if (c == 1) sy[pt] = v; else sz[pt] = v;
    }

    // register copy of own 8 points: floats [24t, 24t+24) = float4 [6t, 6t+6)
    const float4* pb4 = (const float4*)pb;
    float4 a0 = pb4[6*t+0], a1 = pb4[6*t+1], a2 = pb4[6*t+2];
    float4 a3 = pb4[6*t+3], a4 = pb4[6*t+4], a5 = pb4[6*t+5];
    float lx[8], ly[8], lz[8], dist[8];
    lx[0]=a0.x; ly[0]=a0.y; lz[0]=a0.z;
    lx[1]=a0.w; ly[1]=a1.x; lz[1]=a1.y;
    lx[2]=a1.z; ly[2]=a1.w; lz[2]=a2.x;
    lx[3]=a2.y; ly[3]=a2.z; lz[3]=a2.w;
    lx[4]=a3.x; ly[4]=a3.y; lz[4]=a3.z;
    lx[5]=a3.w; ly[5]=a4.x; lz[5]=a4.y;
    lx[6]=a4.z; ly[6]=a4.w; lz[6]=a5.x;
    lx[7]=a5.y; ly[7]=a5.z; lz[7]=a5.w;
#pragma unroll
    for (int j = 0; j < 8; ++j) dist[j] = 1e10f;

    float cx = pb[0], cy = pb[1], cz = pb[2];   // far = 0
    if (t == 0) sidx[0] = 0;
    // NOTE: no pre-loop barrier needed — the step-1 barrier orders staging
    // (writes above) before any sx/sy/sz reads (which occur post-barrier).

    for (int s = 1; s < NPT; ++s) {
        const int par = s & 1;
        // ---- phase A: update (arithmetic identical to passed rounds) ----
        float nd[8];
#pragma unroll
        for (int j = 0; j < 8; ++j) {
            float dx = lx[j]-cx, dy = ly[j]-cy, dz = lz[j]-cz;
            float d = dx*dx + dy*dy + dz*dz;
            nd[j] = fminf(dist[j], d);
            dist[j] = nd[j];
        }
        float lmax = fmaxf(fmaxf(fmaxf(nd[0],nd[1]), fmaxf(nd[2],nd[3])),
                           fmaxf(fmaxf(nd[4],nd[5]), fmaxf(nd[6],nd[7])));
        float bv = lmax;
        bv = fmax_dpp<0xB1>(bv);
        bv = fmax_dpp<0x4E>(bv);
        bv = fmax_dpp<0x141>(bv);
        bv = fmax_dpp<0x140>(bv);
        bv = fmaxf(bv, __shfl_xor(bv, 16));
        bv = fmaxf(bv, __shfl_xor(bv, 32));
        u64 ball = __ballot(lmax == bv);
        int winlane = (int)__builtin_ctzll(ball);
        if (lane == winlane) {
            int cj = 7;
#pragma unroll
            for (int jj = 7; jj >= 0; --jj)
                if (nd[jj] == bv) cj = jj;           // lowest matching j
            slot[par][wave] = ((u64)__float_as_uint(bv) << 32)
                            | (unsigned)(t * 8 + cj);
        }
        __syncthreads();
        // ---- phase B: combine 8 slots (float DPP only) ----
        u64 k = slot[par][lane & 7];
        float v = __uint_as_float((unsigned)(k >> 32));
        float gmax = v;
        gmax = fmax_dpp<0xB1>(gmax);
        gmax = fmax_dpp<0x4E>(gmax);
        gmax = fmax_dpp<0x141>(gmax);
        u64 b2 = __ballot(v == gmax);
        int winslot = (int)__builtin_ctzll(b2);      // lanes 0..7 = slots 0..7
        int widx = __shfl((int)(unsigned)(k & 0xFFFFFFFFull), winslot);
        cx = sx[widx]; cy = sy[widx]; cz = sz[widx];
        if (t == 0) sidx[s] = widx;
    }
    __syncthreads();

    for (int s2 = t; s2 < NPT; s2 += 512) {
        int i = sidx[s2];
        idx_out[b * NPT + s2] = i;
        float* np = newp_out + ((size_t)b * NPT + s2) * 3;
        np[0] = sx[i]; np[1] = sy[i]; np[2] = sz[i];
    }
}

// ---------------------------------------------------------------------------
// K2: KNN. 256 thr/query, thread t owns points 16t..16t+15. 17 extraction
// rounds, 1 barrier each. Slot combine now float-DPP + ballot + shfl (was
// u64-DPP). Removal/rescan wave-uniformly guarded. Tie semantics = lax.top_k.
// ---------------------------------------------------------------------------
__global__ __launch_bounds__(256) void knn_kernel(const float* __restrict__ p,
                                                  const int* __restrict__ idx_in,
                                                  int* __restrict__ knn_out) {
    __shared__ u64 skey[2][4];

    const int blk = blockIdx.x;
    const int b = blk >> 10, n = blk & 1023;
    const int t = threadIdx.x;
    const int lane = t & 63, wave = t >> 6;
    const float* pb = p + (size_t)b * N_ * 3;

    const int qi = idx_in[b * NPT + n];
    const float qx = pb[qi * 3 + 0], qy = pb[qi * 3 + 1], qz = pb[qi * 3 + 2];

    float fl[48];
    const float4* pb4 = (const float4*)pb;
#pragma unroll
    for (int i = 0; i < 12; ++i) {
        float4 v = pb4[t * 12 + i];
        fl[4 * i + 0] = v.x; fl[4 * i + 1] = v.y; fl[4 * i + 2] = v.z; fl[4 * i + 3] = v.w;
    }
    float dist[16];
#pragma unroll
    for (int j = 0; j < 16; ++j) {
        float dx = fl[3 * j + 0] - qx;
        float dy = fl[3 * j + 1] - qy;
        float dz = fl[3 * j + 2] - qz;
        dist[j] = dx * dx + dy * dy + dz * dz;
    }

    float lmin;
    {
        float m0 = fminf(fminf(dist[0], dist[1]), fminf(dist[2], dist[3]));
        float m1 = fminf(fminf(dist[4], dist[5]), fminf(dist[6], dist[7]));
        float m2 = fminf(fminf(dist[8], dist[9]), fminf(dist[10], dist[11]));
        float m3 = fminf(fminf(dist[12], dist[13]), fminf(dist[14], dist[15]));
        lmin = fminf(fminf(m0, m1), fminf(m2, m3));
    }

    int* kout = knn_out + ((size_t)b * NPT + n) * KNNK;

    for (int r = 0; r < 17; ++r) {
        const int par = r & 1;
        float wv = lmin;
        wv = fmin_dpp<0xB1>(wv);
        wv = fmin_dpp<0x4E>(wv);
        wv = fmin_dpp<0x141>(wv);
        wv = fmin_dpp<0x140>(wv);
        wv = fminf(wv, __shfl_xor(wv, 16));
        wv = fminf(wv, __shfl_xor(wv, 32));
        u64 ball = __ballot(lmin == wv);
        int winlane = (int)__builtin_ctzll(ball);
        if (lane == winlane) {
            int j = 15;
#pragma unroll
            for (int jj = 15; jj >= 0; --jj)
                if (dist[jj] == wv) j = jj;          // lowest matching j
            skey[par][wave] = ((u64)__float_as_uint(wv) << 32) | (unsigned)(t * 16 + j);
        }
        __syncthreads();
        u64 k = skey[par][lane & 3];
        float v = __uint_as_float((unsigned)(k >> 32));
        float gmin = v;
        gmin = fmin_dpp<0xB1>(gmin);
        gmin = fmin_dpp<0x4E>(gmin);
        u64 b2 = __ballot(v == gmin);
        int winslot = (int)__builtin_ctzll(b2);      // lanes 0..3 = slots 0..3
        const int widx = __shfl((int)(unsigned)(k & 0xFFFFFFFFull), winslot);
        if (t == 0 && r > 0) kout[r - 1] = widx;
        if ((widx >> 10) == wave) {                  // wave-uniform guard
            if ((widx >> 4) == t) {
#pragma unroll
                for (int jj = 0; jj < 16; ++jj)
                    if ((widx & 15) == jj) dist[jj] = fINF();
                float m0 = fminf(fminf(dist[0], dist[1]), fminf(dist[2], dist[3]));
                float m1 = fminf(fminf(dist[4], dist[5]), fminf(dist[6], dist[7]));
                float m2 = fminf(fminf(dist[8], dist[9]), fminf(dist[10], dist[11]));
                float m3 = fminf(fminf(dist[12], dist[13]), fminf(dist[14], dist[15]));
                lmin = fminf(fminf(m0, m1), fminf(m2, m3));
            }
        }
    }
}

// ---------------------------------------------------------------------------
// K3: second-moment stats (unchanged)
// ---------------------------------------------------------------------------
__global__ __launch_bounds__(256) void stats_kernel(const float* __restrict__ x,
                                                    const int* __restrict__ idx_in,
                                                    const int* __restrict__ knn_in,
                                                    float* __restrict__ part) {
    __shared__ float xc[4 * 64];
    __shared__ float dls[64 * 72];

    const int blk = blockIdx.x;
    const int t = threadIdx.x;
    const int q0 = blk * 64;
    const int b = q0 >> 10;
    const float* xb = x + (size_t)b * N_ * CIN;

    float acc[4][4];
#pragma unroll
    for (int i = 0; i < 4; ++i)
#pragma unroll
        for (int j = 0; j < 4; ++j) acc[i][j] = 0.f;
    float dsum = 0.f;

    const int r0 = (t >> 4) * 4, c0 = (t & 15) * 4;

    for (int sg = 0; sg < 16; ++sg) {
        __syncthreads();
        {
            int qq = t >> 6, c = t & 63;
            int q = q0 + sg * 4 + qq;
            int ci = idx_in[q];
            xc[qq * 64 + c] = xb[ci * CIN + c];
        }
        __syncthreads();
        for (int i = 0; i < 16; ++i) {
            int f = t + 256 * i;
            int qq = f >> 10, k = (f >> 6) & 15, c = f & 63;
            int q = q0 + sg * 4 + qq;
            int row = knn_in[q * KNNK + k];
            dls[(qq * 16 + k) * 72 + c] = xc[qq * 64 + c] - xb[row * CIN + c];
        }
        __syncthreads();
#pragma unroll 4
        for (int s = 0; s < 64; ++s) {
            const float4 a  = *(const float4*)&dls[s * 72 + r0];
            const float4 bb = *(const float4*)&dls[s * 72 + c0];
            acc[0][0] += a.x * bb.x; acc[0][1] += a.x * bb.y; acc[0][2] += a.x * bb.z; acc[0][3] += a.x * bb.w;
            acc[1][0] += a.y * bb.x; acc[1][1] += a.y * bb.y; acc[1][2] += a.y * bb.z; acc[1][3] += a.y * bb.w;
            acc[2][0] += a.z * bb.x; acc[2][1] += a.z * bb.y; acc[2][2] += a.z * bb.z; acc[2][3] += a.z * bb.w;
            acc[3][0] += a.w * bb.x; acc[3][1] += a.w * bb.y; acc[3][2] += a.w * bb.z; acc[3][3] += a.w * bb.w;
        }
        if (t < 64) {
            for (int s = 0; s < 64; ++s) dsum += dls[s * 72 + t];
        }
    }

    float* pout = part + (size_t)blk * 4160;
#pragma unroll
    for (int i = 0; i < 4; ++i)
#pragma unroll
        for (int j = 0; j < 4; ++j)
            pout[(r0 + i) * 64 + (c0 + j)] = acc[i][j];
    if (t < 64) pout[4096 + t] = dsum;
}

__global__ __launch_bounds__(256) void reduce_kernel(const float* __restrict__ part,
                                                     float* __restrict__ M) {
    int e = blockIdx.x * 256 + threadIdx.x;
    if (e >= 4160) return;
    float s = 0.f;
    for (int b = 0; b < 256; ++b) s += part[(size_t)b * 4160 + e];
    M[e] = s;
}

__global__ __launch_bounds__(64) void scale_kernel(const float* __restrict__ M,
                                                   const float* __restrict__ w,
                                                   const float* __restrict__ gamma,
                                                   const float* __restrict__ beta,
                                                   float* __restrict__ st) {
    __shared__ float wv[64];
    const int o = blockIdx.x, t = threadIdx.x;
    wv[t] = w[o * 64 + t];
    __syncthreads();
    const float* Mr = M + t * 64;
    float sr = 0.f;
    for (int c = 0; c < 64; ++c) sr += Mr[c] * wv[c];
    float e2 = wv[t] * sr;
    float mn = wv[t] * M[4096 + t];
#pragma unroll
    for (int off = 32; off >= 1; off >>= 1) {
        e2 += __shfl_xor(e2, off);
        mn += __shfl_xor(mn, off);
    }
    if (t == 0) {
        const float Ns = 262144.0f;
        float mean = mn / Ns;
        float var = e2 / Ns - mean * mean;
        float scale = gamma[o] * rsqrtf(var + 1e-5f);
        st[o] = scale;
        st[128 + o] = beta[o] - mean * scale;
    }
}

// ---------------------------------------------------------------------------
// K5: fused output (unchanged from R2/R4)
// ---------------------------------------------------------------------------
__global__ __launch_bounds__(256) void out_kernel(const float* __restrict__ x,
                                                  const float* __restrict__ w,
                                                  const int* __restrict__ idx_in,
                                                  const int* __restrict__ knn_in,
                                                  const float* __restrict__ st,
                                                  float* __restrict__ out) {
    __shared__ float wT[64 * 132];        // wT[c][o]
    __shared__ float ss[256];
    __shared__ float df4[16 * 260];       // df4[k*260 + c*4 + q]
    __shared__ int   skr[64];
    __shared__ int   sci[4];

    const int blk = blockIdx.x;           // 4096 blocks
    const int b = blk >> 8, n0 = (blk & 255) * 4;
    const int t = threadIdx.x;
    const float* xb = x + (size_t)b * N_ * CIN;

    for (int i = 0; i < 32; ++i) {
        int f = t + 256 * i;
        int o = f >> 6, c = f & 63;
        wT[c * 132 + o] = w[f];
    }
    ss[t] = st[t];
    if (t < 64) skr[t] = knn_in[((size_t)b * NPT + n0) * KNNK + t];
    if (t < 4)  sci[t] = idx_in[b * NPT + n0 + t];
    __syncthreads();

    for (int i = 0; i < 16; ++i) {
        int c = t >> 2, q = t & 3;
        int center = sci[q];
        int row = skr[q * 16 + i];
        df4[i * 260 + c * 4 + q] = xb[center * CIN + c] - xb[row * CIN + c];
    }
    __syncthreads();

    const int k = t & 15, oq = t >> 4;
    float acc[4][8];
#pragma unroll
    for (int q = 0; q < 4; ++q)
#pragma unroll
        for (int i = 0; i < 8; ++i) acc[q][i] = 0.f;

    const float* dr = &df4[k * 260];
    for (int c = 0; c < 64; ++c) {
        const float4 d4 = *(const float4*)&dr[c * 4];
        const float4 w0 = *(const float4*)&wT[c * 132 + oq * 8 + 0];
        const float4 w1 = *(const float4*)&wT[c * 132 + oq * 8 + 4];
        float dv[4] = {d4.x, d4.y, d4.z, d4.w};
        float wvv[8] = {w0.x, w0.y, w0.z, w0.w, w1.x, w1.y, w1.z, w1.w};
#pragma unroll
        for (int q = 0; q < 4; ++q)
#pragma unroll
            for (int i = 0; i < 8; ++i) acc[q][i] += dv[q] * wvv[i];
    }

#pragma unroll
    for (int q = 0; q < 4; ++q)
#pragma unroll
        for (int i = 0; i < 8; ++i) {
            int o = oq * 8 + i;
            float v = fmaxf(acc[q][i] * ss[o] + ss[128 + o], 0.f);
            v = fmax_dpp<0xB1>(v);
            v = fmax_dpp<0x4E>(v);
            v = fmax_dpp<0x141>(v);
            v = fmax_dpp<0x140>(v);
            acc[q][i] = v;
        }
    if (k == 0) {
#pragma unroll
        for (int q = 0; q < 4; ++q) {
            float4 o0 = {acc[q][0], acc[q][1], acc[q][2], acc[q][3]};
            float4 o1 = {acc[q][4], acc[q][5], acc[q][6], acc[q][7]};
            float* op = out + ((size_t)b * NPT + n0 + q) * COUT + oq * 8;
            *(float4*)&op[0] = o0;
            *(float4*)&op[4] = o1;
        }
    }
}

// ---------------------------------------------------------------------------
extern "C" void kernel_launch(void* const* d_in, const int* in_sizes, int n_in,
                              void* d_out, int out_size, void* d_ws, size_t ws_size,
                              hipStream_t stream) {
    const float* x     = (const float*)d_in[0];
    const float* p     = (const float*)d_in[1];
    const float* w     = (const float*)d_in[2];
    const float* gamma = (const float*)d_in[3];
    const float* beta  = (const float*)d_in[4];

    float* out  = (float*)d_out;                               // [16,1024,128]
    float* newp = out + (size_t)B_ * NPT * COUT;               // [16,1024,3]

    char* ws = (char*)d_ws;
    int*   idx  = (int*)(ws + 0);           // 16384 ints
    int*   knn  = (int*)(ws + 65536);       // 262144 ints
    float* part = (float*)(ws + 1114112);   // 256*4160 floats
    float* M    = (float*)(ws + 5373952);   // 4160 floats
    float* st   = (float*)(ws + 5390592);   // 256 floats

    hipLaunchKernelGGL(fps_kernel,   dim3(B_),          dim3(512),  0, stream, p, idx, newp);
    hipLaunchKernelGGL(knn_kernel,   dim3(B_ * NPT),    dim3(256),  0, stream, p, idx, knn);
    hipLaunchKernelGGL(stats_kernel, dim3(256),         dim3(256),  0, stream, x, idx, knn, part);
    hipLaunchKernelGGL(reduce_kernel,dim3(17),          dim3(256),  0, stream, part, M);
    hipLaunchKernelGGL(scale_kernel, dim3(128),         dim3(64),   0, stream, M, w, gamma, beta, st);
    hipLaunchKernelGGL(out_kernel,   dim3(B_ * NPT/4),  dim3(256),  0, stream, x, w, idx, knn, st, out);
}